// Round 8
// baseline (271.319 us; speedup 1.0000x reference)
//
#include <hip/hip_runtime.h>
#include <cstddef>
#include <cstdint>

// Problem constants
#define B_SZ  2
#define T_SEQ 2048
#define S_SEQ 2048
#define C_EMB 1024
#define NH    16
#define HD    64
#define KDIM  1024   // inner dim of the three big GEMMs

typedef __attribute__((ext_vector_type(8))) short bf16x8;
typedef __attribute__((ext_vector_type(4))) float f32x4;

// ---------------------------------------------------------------------------
// Workspace layout (float units).
// ---------------------------------------------------------------------------
#define OFF_XH    ((size_t)0)           // [4096,1024] ushort
#define OFF_XL    ((size_t)2097152)
#define OFF_MEMH  ((size_t)4194304)     // [4096,1024] ushort
#define OFF_MEML  ((size_t)6291456)
#define OFF_QWH   ((size_t)8388608)     // [1024,1024] ushort (transposed [N,K])
#define OFF_QWL   ((size_t)8912896)
#define OFF_KVWH  ((size_t)9437184)     // [2048,1024] ushort
#define OFF_KVWL  ((size_t)10485760)
#define OFF_PWH   ((size_t)11534336)    // [1024,1024] ushort
#define OFF_PWL   ((size_t)12058624)
#define OFF_KSUM  ((size_t)12582912)    // [2,1024]      (zeroed by prep)
#define OFF_MT    ((size_t)12584960)    // [32,64,64]    (zeroed by prep)
#define OFF_TAB   ((size_t)12716032)    // [2048,32] float2
#define OFF_YH    ((size_t)12847104)    // [4096,1024] ushort
#define OFF_YL    ((size_t)14944256)
#define WS_FLOATS ((size_t)17041408)    // ~68.2 MB

__device__ __forceinline__ float elu1(float v) {
    return v > 0.0f ? v + 1.0f : __expf(v);
}
__device__ __forceinline__ unsigned short bf16_rne(float x) {
    union { float f; unsigned int u; } v; v.f = x;
    unsigned int u = v.u;
    return (unsigned short)((u + 0x7FFFu + ((u >> 16) & 1u)) >> 16);
}
__device__ __forceinline__ float bf16_to_f(unsigned short h) {
    union { unsigned int u; float f; } v; v.u = ((unsigned int)h) << 16;
    return v.f;
}

// ---------------------------------------------------------------------------
// Unified prep kernel (block-range dispatch), unchanged.
// ---------------------------------------------------------------------------
#define PREP_BLOCKS 13064

__device__ __forceinline__ void split4_body(
    const float4* __restrict__ in, ushort4* __restrict__ hi,
    ushort4* __restrict__ lo, int i)
{
    float4 v = in[i];
    ushort4 h, l;
    h.x = bf16_rne(v.x); l.x = bf16_rne(v.x - bf16_to_f(h.x));
    h.y = bf16_rne(v.y); l.y = bf16_rne(v.y - bf16_to_f(h.y));
    h.z = bf16_rne(v.z); l.z = bf16_rne(v.z - bf16_to_f(h.z));
    h.w = bf16_rne(v.w); l.w = bf16_rne(v.w - bf16_to_f(h.w));
    hi[i] = h; lo[i] = l;
}

__device__ __forceinline__ void transpose_body(
    const float* __restrict__ W, unsigned short* __restrict__ Wth,
    unsigned short* __restrict__ Wtl, int K, int N, int bx, int by,
    float (*tile)[33])
{
    const int k0 = by * 32, n0 = bx * 32;
    const int tx = threadIdx.x & 31, ty = threadIdx.x >> 5;
    #pragma unroll
    for (int j = 0; j < 4; ++j)
        tile[ty + j * 8][tx] = W[(size_t)(k0 + ty + j * 8) * N + n0 + tx];
    __syncthreads();
    #pragma unroll
    for (int j = 0; j < 4; ++j) {
        float x = tile[tx][ty + j * 8];
        unsigned short h = bf16_rne(x);
        unsigned short l = bf16_rne(x - bf16_to_f(h));
        size_t o = (size_t)(n0 + ty + j * 8) * K + k0 + tx;
        Wth[o] = h; Wtl[o] = l;
    }
}

__global__ __launch_bounds__(256) void prep_kernel(
    const float* __restrict__ x, const float* __restrict__ memory,
    const float* __restrict__ q_w, const float* __restrict__ kv_w,
    const float* __restrict__ proj_w,
    unsigned short* __restrict__ xh, unsigned short* __restrict__ xl,
    unsigned short* __restrict__ mh, unsigned short* __restrict__ ml,
    unsigned short* __restrict__ qwh, unsigned short* __restrict__ qwl,
    unsigned short* __restrict__ kvwh, unsigned short* __restrict__ kvwl,
    unsigned short* __restrict__ pwh, unsigned short* __restrict__ pwl,
    float2* __restrict__ tab, float* __restrict__ zero_base)
{
    __shared__ float tile[32][33];
    const int bid = blockIdx.x;
    const int tid = threadIdx.x;
    if (bid < 4096) {
        split4_body((const float4*)x, (ushort4*)xh, (ushort4*)xl, bid * 256 + tid);
    } else if (bid < 8192) {
        split4_body((const float4*)memory, (ushort4*)mh, (ushort4*)ml, (bid - 4096) * 256 + tid);
    } else if (bid < 9216) {
        int i = bid - 8192;
        transpose_body(q_w, qwh, qwl, 1024, 1024, i & 31, i >> 5, tile);
    } else if (bid < 11264) {
        int i = bid - 9216;
        transpose_body(kv_w, kvwh, kvwl, 1024, 2048, i & 63, i >> 6, tile);
    } else if (bid < 12288) {
        int i = bid - 11264;
        transpose_body(proj_w, pwh, pwl, 1024, 1024, i & 31, i >> 5, tile);
    } else if (bid < 12544) {
        int idx = (bid - 12288) * 256 + tid;    // pos*32 + i
        int pos = idx >> 5, i = idx & 31;
        double invf = exp(-(double)i * (9.210340371976184 / 32.0));  // 10000^(-i/32)
        float arg = (float)((double)pos * invf);
        float sn, cs;
        sincosf(arg, &sn, &cs);
        tab[idx] = make_float2(cs, sn);
    } else {
        int idx = (bid - 12544) * 256 + tid;
        if (idx < 2048 + 131072) zero_base[idx] = 0.0f;   // Ksum + Mt
    }
}

// ---------------------------------------------------------------------------
// 128(M)x64(N) bf16x3 MFMA main loop, 128 threads = 2 waves, each wave owns
// a 64x64 tile (rows w*64..w*64+63). BK=32. Staging split: wave0 stages
// A_h (8 instrs) + B_h (4), wave1 stages A_l + B_l. LDS (ushort):
// As_h[0,4096) As_l[4096,8192) Bs_h[8192,10240) Bs_l[10240,12288) = 24 KB.
// Fills acc[4][4].
// ---------------------------------------------------------------------------
__device__ __forceinline__ void gemm_main_loop_2w(
    const unsigned short* __restrict__ Ah, const unsigned short* __restrict__ Al,
    const unsigned short* __restrict__ Bth, const unsigned short* __restrict__ Btl,
    unsigned short* lds, int m0, int n0, f32x4 acc[4][4])
{
    const int tid = threadIdx.x;
    const int w = tid >> 6, lane = tid & 63;
    const int quad = lane >> 4, lrow = lane & 15;
    const int srow = lane >> 2;           // 0..15
    const int scol = (lane & 3) * 8;      // 0,8,16,24

    // wave0: A_h + B_h; wave1: A_l + B_l
    const unsigned short* gsrcA = ((w == 0) ? Ah : Al) + (size_t)(m0 + srow) * KDIM + scol;
    const unsigned short* gsrcB = ((w == 0) ? Bth : Btl) + (size_t)(n0 + srow) * KDIM + scol;
    unsigned short* lbaseA = &lds[w * 4096];
    unsigned short* lbaseB = &lds[8192 + w * 2048];

    const unsigned short* As_h = lds;
    const unsigned short* As_l = lds + 4096;
    const unsigned short* Bs_h = lds + 8192;
    const unsigned short* Bs_l = lds + 10240;

    for (int k0 = 0; k0 < KDIM; k0 += 32) {
        #pragma unroll
        for (int i = 0; i < 8; ++i)
            __builtin_amdgcn_global_load_lds(
                (const __attribute__((address_space(1))) unsigned int*)(gsrcA + (size_t)i * 16 * KDIM + k0),
                (__attribute__((address_space(3))) unsigned int*)(lbaseA + i * 512),
                16, 0, 0);
        #pragma unroll
        for (int i = 0; i < 4; ++i)
            __builtin_amdgcn_global_load_lds(
                (const __attribute__((address_space(1))) unsigned int*)(gsrcB + (size_t)i * 16 * KDIM + k0),
                (__attribute__((address_space(3))) unsigned int*)(lbaseB + i * 512),
                16, 0, 0);
        __syncthreads();

        bf16x8 bh[4], bl[4];
        #pragma unroll
        for (int jt = 0; jt < 4; ++jt) {
            int nl = jt * 16 + lrow;
            bh[jt] = *(const bf16x8*)&Bs_h[nl * 32 + quad * 8];
            bl[jt] = *(const bf16x8*)&Bs_l[nl * 32 + quad * 8];
        }
        #pragma unroll
        for (int it = 0; it < 4; ++it) {
            int ml = w * 64 + it * 16 + lrow;
            bf16x8 ah = *(const bf16x8*)&As_h[ml * 32 + quad * 8];
            bf16x8 al = *(const bf16x8*)&As_l[ml * 32 + quad * 8];
            #pragma unroll
            for (int jt = 0; jt < 4; ++jt) {
                acc[it][jt] = __builtin_amdgcn_mfma_f32_16x16x32_bf16(ah, bh[jt], acc[it][jt], 0, 0, 0);
                acc[it][jt] = __builtin_amdgcn_mfma_f32_16x16x32_bf16(ah, bl[jt], acc[it][jt], 0, 0, 0);
                acc[it][jt] = __builtin_amdgcn_mfma_f32_16x16x32_bf16(al, bh[jt], acc[it][jt], 0, 0, 0);
            }
        }
        __syncthreads();
    }
}

// ---------------------------------------------------------------------------
// KV GEMM (unchanged from R7): 128x128 head-paired tile, BK=64,
// fused elu/Ksum/rope + Mt accumulate. grid (16 heads, 32 mtiles), 256 thr.
// ---------------------------------------------------------------------------
__global__ __launch_bounds__(256) void gemm_kv(
    const unsigned short* __restrict__ Ah, const unsigned short* __restrict__ Al,
    const unsigned short* __restrict__ Bth, const unsigned short* __restrict__ Btl,
    const float* __restrict__ bias, const float2* __restrict__ tab,
    float* __restrict__ Ksum, float* __restrict__ Mt)
{
    __shared__ unsigned short smem[34816];
    const int tid = threadIdx.x;
    const int w = tid >> 6, lane = tid & 63;
    const int wr = w >> 1, wc = w & 1;
    const int quad = lane >> 4, lrow = lane & 15;
    const int h  = blockIdx.x;
    const int m0 = blockIdx.y * 128;
    const int b  = m0 >> 11;
    const int tbase = (m0 & 2047) + wr * 64;

    {
        const unsigned short* src = (w == 0) ? Ah : (w == 1) ? Al : (w == 2) ? Bth : Btl;
        const int srow = lane >> 2, scol = (lane & 3) * 8;
        const size_t rowbase = (w < 2) ? (size_t)(m0 + srow) : (size_t)(h * 64 + srow);
        const unsigned short* gsrc = src + rowbase * KDIM + scol;
        const size_t vskip = (w >= 2) ? (size_t)960 * KDIM : 0;
        unsigned short* lbase = &smem[w * 8192];
        const unsigned short* As_h = smem;
        const unsigned short* As_l = smem + 8192;
        const unsigned short* Bs_h = smem + 16384;
        const unsigned short* Bs_l = smem + 24576;

        f32x4 acc[4][4] = {};
        for (int k0 = 0; k0 < KDIM; k0 += 64) {
            #pragma unroll
            for (int p = 0; p < 2; ++p)
                #pragma unroll
                for (int i = 0; i < 8; ++i) {
                    size_t goff = (size_t)i * 16 * KDIM + k0 + p * 32 + ((i >= 4) ? vskip : 0);
                    __builtin_amdgcn_global_load_lds(
                        (const __attribute__((address_space(1))) unsigned int*)(gsrc + goff),
                        (__attribute__((address_space(3))) unsigned int*)(lbase + p * 4096 + i * 512),
                        16, 0, 0);
                }
            __syncthreads();
            #pragma unroll
            for (int p = 0; p < 2; ++p) {
                bf16x8 bh[4], bl[4];
                #pragma unroll
                for (int jt = 0; jt < 4; ++jt) {
                    int nl = wc * 64 + jt * 16 + lrow;
                    bh[jt] = *(const bf16x8*)&Bs_h[p * 4096 + nl * 32 + quad * 8];
                    bl[jt] = *(const bf16x8*)&Bs_l[p * 4096 + nl * 32 + quad * 8];
                }
                #pragma unroll
                for (int it = 0; it < 4; ++it) {
                    int ml = wr * 64 + it * 16 + lrow;
                    bf16x8 ah = *(const bf16x8*)&As_h[p * 4096 + ml * 32 + quad * 8];
                    bf16x8 al = *(const bf16x8*)&As_l[p * 4096 + ml * 32 + quad * 8];
                    #pragma unroll
                    for (int jt = 0; jt < 4; ++jt) {
                        acc[it][jt] = __builtin_amdgcn_mfma_f32_16x16x32_bf16(ah, bh[jt], acc[it][jt], 0, 0, 0);
                        acc[it][jt] = __builtin_amdgcn_mfma_f32_16x16x32_bf16(ah, bl[jt], acc[it][jt], 0, 0, 0);
                        acc[it][jt] = __builtin_amdgcn_mfma_f32_16x16x32_bf16(al, bh[jt], acc[it][jt], 0, 0, 0);
                    }
                }
            }
            __syncthreads();
        }

        const bool isK = (wc == 0);
        const int colg = (isK ? 0 : C_EMB) + h * 64;
        float bb[4];
        #pragma unroll
        for (int jt = 0; jt < 4; ++jt) bb[jt] = bias[colg + jt * 16 + lrow];
        #pragma unroll
        for (int it = 0; it < 4; ++it)
            #pragma unroll
            for (int jt = 0; jt < 4; ++jt)
                #pragma unroll
                for (int r = 0; r < 4; ++r) {
                    float v = acc[it][jt][r] + bb[jt];
                    acc[it][jt][r] = isK ? elu1(v) : v;
                }

        if (isK) {
            #pragma unroll
            for (int jt = 0; jt < 4; ++jt) {
                float p = 0.0f;
                #pragma unroll
                for (int it = 0; it < 4; ++it)
                    #pragma unroll
                    for (int r = 0; r < 4; ++r) p += acc[it][jt][r];
                p += __shfl_xor(p, 16);
                p += __shfl_xor(p, 32);
                if (quad == 0)
                    atomicAdd(&Ksum[b * C_EMB + h * 64 + jt * 16 + lrow], p);
            }
            #pragma unroll
            for (int it = 0; it < 4; ++it)
                #pragma unroll
                for (int r = 0; r < 4; ++r) {
                    int s = tbase + it * 16 + quad * 4 + r;
                    float2 c0 = tab[s * 32 + lrow];
                    float2 c1 = tab[s * 32 + 16 + lrow];
                    float a0 = acc[it][0][r], a1 = acc[it][1][r];
                    float a2 = acc[it][2][r], a3 = acc[it][3][r];
                    acc[it][0][r] = a0 * c0.x - a2 * c0.y;
                    acc[it][2][r] = a2 * c0.x + a0 * c0.y;
                    acc[it][1][r] = a1 * c1.x - a3 * c1.y;
                    acc[it][3][r] = a3 * c1.x + a1 * c1.y;
                }
        }

        // transposed LDS: K_hi[64][136] @0, K_lo @8704, V_hi @17408, V_lo @26112
        unsigned short* Hd = smem + (isK ? 0 : 17408);
        unsigned short* Ld = Hd + 8704;
        #pragma unroll
        for (int jt = 0; jt < 4; ++jt) {
            int d = jt * 16 + lrow;
            #pragma unroll
            for (int it = 0; it < 4; ++it) {
                int t0loc = wr * 64 + it * 16 + quad * 4;
                ushort4 h4, l4;
                float v0 = acc[it][jt][0], v1 = acc[it][jt][1];
                float v2 = acc[it][jt][2], v3 = acc[it][jt][3];
                h4.x = bf16_rne(v0); l4.x = bf16_rne(v0 - bf16_to_f(h4.x));
                h4.y = bf16_rne(v1); l4.y = bf16_rne(v1 - bf16_to_f(h4.y));
                h4.z = bf16_rne(v2); l4.z = bf16_rne(v2 - bf16_to_f(h4.z));
                h4.w = bf16_rne(v3); l4.w = bf16_rne(v3 - bf16_to_f(h4.w));
                *(ushort4*)&Hd[d * 136 + t0loc] = h4;
                *(ushort4*)&Ld[d * 136 + t0loc] = l4;
            }
        }
    }
    __syncthreads();

    {
        const unsigned short* KH = smem;
        const unsigned short* KL = smem + 8704;
        const unsigned short* VH = smem + 17408;
        const unsigned short* VL = smem + 26112;
        const int mrow = w * 16 + lrow;
        f32x4 macc[4] = {};
        #pragma unroll
        for (int ks = 0; ks < 4; ++ks) {
            int kof = ks * 32 + quad * 8;
            bf16x8 vah = *(const bf16x8*)&VH[mrow * 136 + kof];
            bf16x8 val = *(const bf16x8*)&VL[mrow * 136 + kof];
            #pragma unroll
            for (int jt = 0; jt < 4; ++jt) {
                int nrow = jt * 16 + lrow;
                bf16x8 kbh = *(const bf16x8*)&KH[nrow * 136 + kof];
                bf16x8 kbl = *(const bf16x8*)&KL[nrow * 136 + kof];
                macc[jt] = __builtin_amdgcn_mfma_f32_16x16x32_bf16(vah, kbh, macc[jt], 0, 0, 0);
                macc[jt] = __builtin_amdgcn_mfma_f32_16x16x32_bf16(vah, kbl, macc[jt], 0, 0, 0);
                macc[jt] = __builtin_amdgcn_mfma_f32_16x16x32_bf16(val, kbh, macc[jt], 0, 0, 0);
            }
        }
        const int bh = b * NH + h;
        #pragma unroll
        for (int jt = 0; jt < 4; ++jt)
            #pragma unroll
            for (int r = 0; r < 4; ++r)
                atomicAdd(&Mt[((size_t)bh * 64 + w * 16 + quad * 4 + r) * 64 + jt * 16 + lrow],
                          macc[jt][r]);
    }
}

// ---------------------------------------------------------------------------
// Q GEMM, 128x64 tile (one head per block), 128 threads = 2 waves of 64x64.
// grid (16 heads, 32 mtiles) = 512 blocks. Epilogue: bias, elu+1, den in
// regs, RoPE, per-wave Qrot LDS, Y = (Qrot @ Mt^T)/den, bf16 hi/lo stores.
// LDS 36 KB (main loop 24 KB; epilogue per-wave Qrot [64][72] hi/lo).
// ---------------------------------------------------------------------------
__global__ __launch_bounds__(128) void gemm_q(
    const unsigned short* __restrict__ Ah, const unsigned short* __restrict__ Al,
    const unsigned short* __restrict__ Bth, const unsigned short* __restrict__ Btl,
    const float* __restrict__ bias, const float2* __restrict__ tab,
    const float* __restrict__ Ksum, const float* __restrict__ Mt,
    unsigned short* __restrict__ Yh, unsigned short* __restrict__ Yl)
{
    __shared__ unsigned short smem[18432];   // 36 KB
    const int h  = blockIdx.x;
    const int m0 = blockIdx.y * 128;
    f32x4 acc[4][4] = {};
    gemm_main_loop_2w(Ah, Al, Bth, Btl, smem, m0, h * 64, acc);

    const int tid = threadIdx.x;
    const int w = tid >> 6, lane = tid & 63;
    const int quad = lane >> 4, lrow = lane & 15;
    const int b = m0 >> 11;
    const int tbase = (m0 & 2047) + w * 64;
    const int bh = b * NH + h;

    float bb[4];
    #pragma unroll
    for (int jt = 0; jt < 4; ++jt) bb[jt] = bias[h * 64 + jt * 16 + lrow];
    #pragma unroll
    for (int it = 0; it < 4; ++it)
        #pragma unroll
        for (int jt = 0; jt < 4; ++jt)
            #pragma unroll
            for (int r = 0; r < 4; ++r)
                acc[it][jt][r] = elu1(acc[it][jt][r] + bb[jt]);

    // den (pre-rope), kept in registers
    float ks[4], den_reg[4][4];
    #pragma unroll
    for (int jt = 0; jt < 4; ++jt) ks[jt] = Ksum[b * C_EMB + h * 64 + jt * 16 + lrow];
    #pragma unroll
    for (int it = 0; it < 4; ++it)
        #pragma unroll
        for (int r = 0; r < 4; ++r) {
            float p = acc[it][0][r] * ks[0] + acc[it][1][r] * ks[1]
                    + acc[it][2][r] * ks[2] + acc[it][3][r] * ks[3];
            p += __shfl_xor(p, 1);
            p += __shfl_xor(p, 2);
            p += __shfl_xor(p, 4);
            p += __shfl_xor(p, 8);
            den_reg[it][r] = p;
        }

    // RoPE in registers (pairs jt, jt^2)
    #pragma unroll
    for (int it = 0; it < 4; ++it)
        #pragma unroll
        for (int r = 0; r < 4; ++r) {
            int s = tbase + it * 16 + quad * 4 + r;
            float2 c0 = tab[s * 32 + lrow];
            float2 c1 = tab[s * 32 + 16 + lrow];
            float a0 = acc[it][0][r], a1 = acc[it][1][r];
            float a2 = acc[it][2][r], a3 = acc[it][3][r];
            acc[it][0][r] = a0 * c0.x - a2 * c0.y;
            acc[it][2][r] = a2 * c0.x + a0 * c0.y;
            acc[it][1][r] = a1 * c1.x - a3 * c1.y;
            acc[it][3][r] = a3 * c1.x + a1 * c1.y;
        }

    // Qrot -> per-wave LDS ([64 rows][72], hi then lo). Wave-private region;
    // main loop's final __syncthreads drained cross-wave LDS reads.
    unsigned short* QH = smem + w * 9216;
    unsigned short* QL = QH + 4608;
    #pragma unroll
    for (int it = 0; it < 4; ++it)
        #pragma unroll
        for (int jt = 0; jt < 4; ++jt)
            #pragma unroll
            for (int r = 0; r < 4; ++r) {
                int tloc = it * 16 + quad * 4 + r;
                int d = jt * 16 + lrow;
                float v = acc[it][jt][r];
                unsigned short hh = bf16_rne(v);
                QH[tloc * 72 + d] = hh;
                QL[tloc * 72 + d] = bf16_rne(v - bf16_to_f(hh));
            }

    // Y = (Qrot @ Mt^T) / den
    f32x4 acc2[4][4] = {};
    #pragma unroll
    for (int kc = 0; kc < 2; ++kc) {
        bf16x8 mbh[4], mbl[4];
        #pragma unroll
        for (int jt2 = 0; jt2 < 4; ++jt2) {
            const float* mp = &Mt[((size_t)bh * 64 + jt2 * 16 + lrow) * 64 + kc * 32 + quad * 8];
            #pragma unroll
            for (int e = 0; e < 8; ++e) {
                float x = mp[e];
                unsigned short hh = bf16_rne(x);
                mbh[jt2][e] = (short)hh;
                mbl[jt2][e] = (short)bf16_rne(x - bf16_to_f(hh));
            }
        }
        #pragma unroll
        for (int it2 = 0; it2 < 4; ++it2) {
            int ro = (it2 * 16 + lrow) * 72 + kc * 32 + quad * 8;
            bf16x8 qh = *(const bf16x8*)&QH[ro];
            bf16x8 ql = *(const bf16x8*)&QL[ro];
            #pragma unroll
            for (int jt2 = 0; jt2 < 4; ++jt2) {
                acc2[it2][jt2] = __builtin_amdgcn_mfma_f32_16x16x32_bf16(qh, mbh[jt2], acc2[it2][jt2], 0, 0, 0);
                acc2[it2][jt2] = __builtin_amdgcn_mfma_f32_16x16x32_bf16(qh, mbl[jt2], acc2[it2][jt2], 0, 0, 0);
                acc2[it2][jt2] = __builtin_amdgcn_mfma_f32_16x16x32_bf16(ql, mbh[jt2], acc2[it2][jt2], 0, 0, 0);
            }
        }
    }

    // divide + bf16 hi/lo store
    #pragma unroll
    for (int it2 = 0; it2 < 4; ++it2)
        #pragma unroll
        for (int jt2 = 0; jt2 < 4; ++jt2)
            #pragma unroll
            for (int r = 0; r < 4; ++r) {
                float v = acc2[it2][jt2][r] / den_reg[it2][r];
                size_t o = ((size_t)(m0 + w * 64 + it2 * 16 + quad * 4 + r)) * C_EMB
                         + h * 64 + jt2 * 16 + lrow;
                unsigned short hh = bf16_rne(v);
                Yh[o] = hh;
                Yl[o] = bf16_rne(v - bf16_to_f(hh));
            }
}

// ---------------------------------------------------------------------------
// Output projection GEMM, 128x64 tile, 128 threads = 2 waves of 64x64.
// grid (16 n-tiles, 32 m-tiles) = 512 blocks. LDS 24 KB.
// ---------------------------------------------------------------------------
__global__ __launch_bounds__(128) void gemm_out(
    const unsigned short* __restrict__ Ah, const unsigned short* __restrict__ Al,
    const unsigned short* __restrict__ Bth, const unsigned short* __restrict__ Btl,
    const float* __restrict__ bias, float* __restrict__ out)
{
    __shared__ unsigned short lds[12288];    // 24 KB
    const int m0 = blockIdx.y * 128, n0 = blockIdx.x * 64;
    f32x4 acc[4][4] = {};
    gemm_main_loop_2w(Ah, Al, Bth, Btl, lds, m0, n0, acc);

    const int tid = threadIdx.x;
    const int w = tid >> 6, lane = tid & 63;
    const int quad = lane >> 4, lrow = lane & 15;

    #pragma unroll
    for (int jt = 0; jt < 4; ++jt) {
        int gc = n0 + jt * 16 + lrow;
        float bb = bias[gc];
        #pragma unroll
        for (int it = 0; it < 4; ++it) {
            int grb = m0 + w * 64 + it * 16 + quad * 4;
            #pragma unroll
            for (int r = 0; r < 4; ++r)
                out[(size_t)(grb + r) * C_EMB + gc] = acc[it][jt][r] + bb;
        }
    }
}

// ---------------------------------------------------------------------------
extern "C" void kernel_launch(void* const* d_in, const int* in_sizes, int n_in,
                              void* d_out, int out_size, void* d_ws, size_t ws_size,
                              hipStream_t stream)
{
    const float* x      = (const float*)d_in[0];
    const float* memory = (const float*)d_in[1];
    const float* q_w    = (const float*)d_in[2];
    const float* q_b    = (const float*)d_in[3];
    const float* kv_w   = (const float*)d_in[4];
    const float* kv_b   = (const float*)d_in[5];
    const float* proj_w = (const float*)d_in[6];
    const float* proj_b = (const float*)d_in[7];

    if (ws_size < WS_FLOATS * sizeof(float)) return;

    float* ws = (float*)d_ws;
    unsigned short* xh   = (unsigned short*)(ws + OFF_XH);
    unsigned short* xl   = (unsigned short*)(ws + OFF_XL);
    unsigned short* mh   = (unsigned short*)(ws + OFF_MEMH);
    unsigned short* ml   = (unsigned short*)(ws + OFF_MEML);
    unsigned short* qwh  = (unsigned short*)(ws + OFF_QWH);
    unsigned short* qwl  = (unsigned short*)(ws + OFF_QWL);
    unsigned short* kvwh = (unsigned short*)(ws + OFF_KVWH);
    unsigned short* kvwl = (unsigned short*)(ws + OFF_KVWL);
    unsigned short* pwh  = (unsigned short*)(ws + OFF_PWH);
    unsigned short* pwl  = (unsigned short*)(ws + OFF_PWL);
    unsigned short* Yh   = (unsigned short*)(ws + OFF_YH);
    unsigned short* Yl   = (unsigned short*)(ws + OFF_YL);
    float*  Ksum = ws + OFF_KSUM;
    float*  Mm   = ws + OFF_MT;
    float2* tab  = (float2*)(ws + OFF_TAB);

    // One prep dispatch: splits + weight transposes + rope table + zero Ksum/Mt
    prep_kernel<<<PREP_BLOCKS, 256, 0, stream>>>(
        x, memory, q_w, kv_w, proj_w,
        xh, xl, mh, ml, qwh, qwl, kvwh, kvwl, pwh, pwl,
        tab, Ksum /* zero_base: Ksum+Mt contiguous */);

    // KV GEMM (+elu/Ksum/rope + fused Mt accumulate). No K/V global output.
    gemm_kv<<<dim3(16, 32), 256, 0, stream>>>(mh, ml, kvwh, kvwl, kv_b, tab, Ksum, Mm);
    // Q GEMM (+elu/den/rope + fused Y = Qrot·Mt^T/den) -> Yh/Yl. 512x128.
    gemm_q<<<dim3(16, 32), 128, 0, stream>>>(xh, xl, qwh, qwl, q_b, tab, Ksum, Mm, Yh, Yl);
    // out = Y @ proj_w + proj_b. 512x128.
    gemm_out<<<dim3(16, 32), 128, 0, stream>>>(Yh, Yl, pwh, pwl, proj_b, (float*)d_out);
}

// Round 9
// 251.817 us; speedup vs baseline: 1.0774x; 1.0774x over previous
//
#include <hip/hip_runtime.h>
#include <cstddef>
#include <cstdint>

// Problem constants
#define B_SZ  2
#define T_SEQ 2048
#define S_SEQ 2048
#define C_EMB 1024
#define NH    16
#define HD    64
#define KDIM  1024   // inner dim of the three big GEMMs

typedef __attribute__((ext_vector_type(8))) short bf16x8;
typedef __attribute__((ext_vector_type(4))) float f32x4;

// ---------------------------------------------------------------------------
// Workspace layout (float units).
// ---------------------------------------------------------------------------
#define OFF_XH    ((size_t)0)           // [4096,1024] ushort
#define OFF_XL    ((size_t)2097152)
#define OFF_MEMH  ((size_t)4194304)     // [4096,1024] ushort
#define OFF_MEML  ((size_t)6291456)
#define OFF_QWH   ((size_t)8388608)     // [1024,1024] ushort (transposed [N,K])
#define OFF_QWL   ((size_t)8912896)
#define OFF_KVWH  ((size_t)9437184)     // [2048,1024] ushort
#define OFF_KVWL  ((size_t)10485760)
#define OFF_PWH   ((size_t)11534336)    // [1024,1024] ushort
#define OFF_PWL   ((size_t)12058624)
#define OFF_KSUM  ((size_t)12582912)    // [2,1024]      (zeroed by prep)
#define OFF_MT    ((size_t)12584960)    // [32,64,64]    (zeroed by prep)
#define OFF_TAB   ((size_t)12716032)    // [2048,32] float2
#define OFF_YH    ((size_t)12847104)    // [4096,1024] ushort
#define OFF_YL    ((size_t)14944256)
#define WS_FLOATS ((size_t)17041408)    // ~68.2 MB

__device__ __forceinline__ float elu1(float v) {
    return v > 0.0f ? v + 1.0f : __expf(v);
}
__device__ __forceinline__ unsigned short bf16_rne(float x) {
    union { float f; unsigned int u; } v; v.f = x;
    unsigned int u = v.u;
    return (unsigned short)((u + 0x7FFFu + ((u >> 16) & 1u)) >> 16);
}
__device__ __forceinline__ float bf16_to_f(unsigned short h) {
    union { unsigned int u; float f; } v; v.u = ((unsigned int)h) << 16;
    return v.f;
}

// ---------------------------------------------------------------------------
// Unified prep kernel (block-range dispatch).
//   [0,4096)       x split
//   [4096,8192)    memory split
//   [8192,9216)    q_w split+transpose
//   [9216,11264)   kv_w split+transpose
//   [11264,12288)  proj_w split+transpose
//   [12288,12544)  rope table
//   [12544,13064)  zero Ksum+Mt
//   [13064,17160)  d_out = broadcast proj_b (bias base for atomic K-split out)
// ---------------------------------------------------------------------------
#define PREP_BLOCKS 17160

__device__ __forceinline__ void split4_body(
    const float4* __restrict__ in, ushort4* __restrict__ hi,
    ushort4* __restrict__ lo, int i)
{
    float4 v = in[i];
    ushort4 h, l;
    h.x = bf16_rne(v.x); l.x = bf16_rne(v.x - bf16_to_f(h.x));
    h.y = bf16_rne(v.y); l.y = bf16_rne(v.y - bf16_to_f(h.y));
    h.z = bf16_rne(v.z); l.z = bf16_rne(v.z - bf16_to_f(h.z));
    h.w = bf16_rne(v.w); l.w = bf16_rne(v.w - bf16_to_f(h.w));
    hi[i] = h; lo[i] = l;
}

__device__ __forceinline__ void transpose_body(
    const float* __restrict__ W, unsigned short* __restrict__ Wth,
    unsigned short* __restrict__ Wtl, int K, int N, int bx, int by,
    float (*tile)[33])
{
    const int k0 = by * 32, n0 = bx * 32;
    const int tx = threadIdx.x & 31, ty = threadIdx.x >> 5;
    #pragma unroll
    for (int j = 0; j < 4; ++j)
        tile[ty + j * 8][tx] = W[(size_t)(k0 + ty + j * 8) * N + n0 + tx];
    __syncthreads();
    #pragma unroll
    for (int j = 0; j < 4; ++j) {
        float x = tile[tx][ty + j * 8];
        unsigned short h = bf16_rne(x);
        unsigned short l = bf16_rne(x - bf16_to_f(h));
        size_t o = (size_t)(n0 + ty + j * 8) * K + k0 + tx;
        Wth[o] = h; Wtl[o] = l;
    }
}

__global__ __launch_bounds__(256) void prep_kernel(
    const float* __restrict__ x, const float* __restrict__ memory,
    const float* __restrict__ q_w, const float* __restrict__ kv_w,
    const float* __restrict__ proj_w, const float* __restrict__ proj_b,
    unsigned short* __restrict__ xh, unsigned short* __restrict__ xl,
    unsigned short* __restrict__ mh, unsigned short* __restrict__ ml,
    unsigned short* __restrict__ qwh, unsigned short* __restrict__ qwl,
    unsigned short* __restrict__ kvwh, unsigned short* __restrict__ kvwl,
    unsigned short* __restrict__ pwh, unsigned short* __restrict__ pwl,
    float2* __restrict__ tab, float* __restrict__ zero_base,
    float* __restrict__ outp)
{
    __shared__ float tile[32][33];
    const int bid = blockIdx.x;
    const int tid = threadIdx.x;
    if (bid < 4096) {
        split4_body((const float4*)x, (ushort4*)xh, (ushort4*)xl, bid * 256 + tid);
    } else if (bid < 8192) {
        split4_body((const float4*)memory, (ushort4*)mh, (ushort4*)ml, (bid - 4096) * 256 + tid);
    } else if (bid < 9216) {
        int i = bid - 8192;
        transpose_body(q_w, qwh, qwl, 1024, 1024, i & 31, i >> 5, tile);
    } else if (bid < 11264) {
        int i = bid - 9216;
        transpose_body(kv_w, kvwh, kvwl, 1024, 2048, i & 63, i >> 6, tile);
    } else if (bid < 12288) {
        int i = bid - 11264;
        transpose_body(proj_w, pwh, pwl, 1024, 1024, i & 31, i >> 5, tile);
    } else if (bid < 12544) {
        int idx = (bid - 12288) * 256 + tid;    // pos*32 + i
        int pos = idx >> 5, i = idx & 31;
        double invf = exp(-(double)i * (9.210340371976184 / 32.0));  // 10000^(-i/32)
        float arg = (float)((double)pos * invf);
        float sn, cs;
        sincosf(arg, &sn, &cs);
        tab[idx] = make_float2(cs, sn);
    } else if (bid < 13064) {
        int idx = (bid - 12544) * 256 + tid;
        if (idx < 2048 + 131072) zero_base[idx] = 0.0f;   // Ksum + Mt
    } else {
        // bias base for K-split output: out[r][c] = proj_b[c]
        int f = (bid - 13064) * 256 + tid;               // float4 index, 1M total
        ((float4*)outp)[f] = ((const float4*)proj_b)[f & 255];
    }
}

// ---------------------------------------------------------------------------
// 128(M)x64(N) bf16x3 MFMA main loop, BK=64 (two 32-wide K-panels per
// barrier). 256 threads, wave w owns rows w*32..w*32+31 x all 64 cols.
// LDS: As_h[0,8192) As_l[8192,16384) Bs_h[16384,20480) Bs_l[20480,24576).
// Fills acc[2][4]. (R7 config — 2048 wave-tiles, 8 waves/CU.)
// ---------------------------------------------------------------------------
__device__ __forceinline__ void gemm_main_loop_64(
    const unsigned short* __restrict__ Ah, const unsigned short* __restrict__ Al,
    const unsigned short* __restrict__ Bth, const unsigned short* __restrict__ Btl,
    unsigned short* lds, int m0, int n0, f32x4 acc[2][4])
{
    const int tid = threadIdx.x;
    const int w = tid >> 6, lane = tid & 63;
    const int quad = lane >> 4, lrow = lane & 15;
    const int srow = lane >> 2;
    const int scol = (lane & 3) * 8;

    const unsigned short* src = (w == 0) ? Ah : (w == 1) ? Al : (w == 2) ? Bth : Btl;
    const int rbase = (w < 2) ? m0 : n0;
    const unsigned short* gsrc = src + (size_t)(rbase + srow) * KDIM + scol;
    unsigned short* lbase = (w < 2) ? &lds[w * 8192] : &lds[16384 + (w - 2) * 4096];

    const unsigned short* As_h = lds;
    const unsigned short* As_l = lds + 8192;
    const unsigned short* Bs_h = lds + 16384;
    const unsigned short* Bs_l = lds + 20480;

    for (int k0 = 0; k0 < KDIM; k0 += 64) {
        if (w < 2) {
            #pragma unroll
            for (int p = 0; p < 2; ++p)
                #pragma unroll
                for (int i = 0; i < 8; ++i)
                    __builtin_amdgcn_global_load_lds(
                        (const __attribute__((address_space(1))) unsigned int*)(gsrc + (size_t)i * 16 * KDIM + k0 + p * 32),
                        (__attribute__((address_space(3))) unsigned int*)(lbase + p * 4096 + i * 512),
                        16, 0, 0);
        } else {
            #pragma unroll
            for (int p = 0; p < 2; ++p)
                #pragma unroll
                for (int i = 0; i < 4; ++i)
                    __builtin_amdgcn_global_load_lds(
                        (const __attribute__((address_space(1))) unsigned int*)(gsrc + (size_t)i * 16 * KDIM + k0 + p * 32),
                        (__attribute__((address_space(3))) unsigned int*)(lbase + p * 2048 + i * 512),
                        16, 0, 0);
        }
        __syncthreads();

        #pragma unroll
        for (int p = 0; p < 2; ++p) {
            bf16x8 bh[4], bl[4];
            #pragma unroll
            for (int jt = 0; jt < 4; ++jt) {
                int nl = jt * 16 + lrow;
                bh[jt] = *(const bf16x8*)&Bs_h[p * 2048 + nl * 32 + quad * 8];
                bl[jt] = *(const bf16x8*)&Bs_l[p * 2048 + nl * 32 + quad * 8];
            }
            #pragma unroll
            for (int it = 0; it < 2; ++it) {
                int ml = w * 32 + it * 16 + lrow;
                bf16x8 ah = *(const bf16x8*)&As_h[p * 4096 + ml * 32 + quad * 8];
                bf16x8 al = *(const bf16x8*)&As_l[p * 4096 + ml * 32 + quad * 8];
                #pragma unroll
                for (int jt = 0; jt < 4; ++jt) {
                    acc[it][jt] = __builtin_amdgcn_mfma_f32_16x16x32_bf16(ah, bh[jt], acc[it][jt], 0, 0, 0);
                    acc[it][jt] = __builtin_amdgcn_mfma_f32_16x16x32_bf16(ah, bl[jt], acc[it][jt], 0, 0, 0);
                    acc[it][jt] = __builtin_amdgcn_mfma_f32_16x16x32_bf16(al, bh[jt], acc[it][jt], 0, 0, 0);
                }
            }
        }
        __syncthreads();
    }
}

// ---------------------------------------------------------------------------
// KV GEMM: 128x128 head-paired tile, BK=64, fused elu/Ksum/rope + Mt
// accumulate. grid (16 heads, 32 mtiles), 256 threads. (Unchanged.)
// ---------------------------------------------------------------------------
__global__ __launch_bounds__(256) void gemm_kv(
    const unsigned short* __restrict__ Ah, const unsigned short* __restrict__ Al,
    const unsigned short* __restrict__ Bth, const unsigned short* __restrict__ Btl,
    const float* __restrict__ bias, const float2* __restrict__ tab,
    float* __restrict__ Ksum, float* __restrict__ Mt)
{
    __shared__ unsigned short smem[34816];
    const int tid = threadIdx.x;
    const int w = tid >> 6, lane = tid & 63;
    const int wr = w >> 1, wc = w & 1;
    const int quad = lane >> 4, lrow = lane & 15;
    const int h  = blockIdx.x;
    const int m0 = blockIdx.y * 128;
    const int b  = m0 >> 11;
    const int tbase = (m0 & 2047) + wr * 64;

    {
        const unsigned short* src = (w == 0) ? Ah : (w == 1) ? Al : (w == 2) ? Bth : Btl;
        const int srow = lane >> 2, scol = (lane & 3) * 8;
        const size_t rowbase = (w < 2) ? (size_t)(m0 + srow) : (size_t)(h * 64 + srow);
        const unsigned short* gsrc = src + rowbase * KDIM + scol;
        const size_t vskip = (w >= 2) ? (size_t)960 * KDIM : 0;
        unsigned short* lbase = &smem[w * 8192];
        const unsigned short* As_h = smem;
        const unsigned short* As_l = smem + 8192;
        const unsigned short* Bs_h = smem + 16384;
        const unsigned short* Bs_l = smem + 24576;

        f32x4 acc[4][4] = {};
        for (int k0 = 0; k0 < KDIM; k0 += 64) {
            #pragma unroll
            for (int p = 0; p < 2; ++p)
                #pragma unroll
                for (int i = 0; i < 8; ++i) {
                    size_t goff = (size_t)i * 16 * KDIM + k0 + p * 32 + ((i >= 4) ? vskip : 0);
                    __builtin_amdgcn_global_load_lds(
                        (const __attribute__((address_space(1))) unsigned int*)(gsrc + goff),
                        (__attribute__((address_space(3))) unsigned int*)(lbase + p * 4096 + i * 512),
                        16, 0, 0);
                }
            __syncthreads();
            #pragma unroll
            for (int p = 0; p < 2; ++p) {
                bf16x8 bh[4], bl[4];
                #pragma unroll
                for (int jt = 0; jt < 4; ++jt) {
                    int nl = wc * 64 + jt * 16 + lrow;
                    bh[jt] = *(const bf16x8*)&Bs_h[p * 4096 + nl * 32 + quad * 8];
                    bl[jt] = *(const bf16x8*)&Bs_l[p * 4096 + nl * 32 + quad * 8];
                }
                #pragma unroll
                for (int it = 0; it < 4; ++it) {
                    int ml = wr * 64 + it * 16 + lrow;
                    bf16x8 ah = *(const bf16x8*)&As_h[p * 4096 + ml * 32 + quad * 8];
                    bf16x8 al = *(const bf16x8*)&As_l[p * 4096 + ml * 32 + quad * 8];
                    #pragma unroll
                    for (int jt = 0; jt < 4; ++jt) {
                        acc[it][jt] = __builtin_amdgcn_mfma_f32_16x16x32_bf16(ah, bh[jt], acc[it][jt], 0, 0, 0);
                        acc[it][jt] = __builtin_amdgcn_mfma_f32_16x16x32_bf16(ah, bl[jt], acc[it][jt], 0, 0, 0);
                        acc[it][jt] = __builtin_amdgcn_mfma_f32_16x16x32_bf16(al, bh[jt], acc[it][jt], 0, 0, 0);
                    }
                }
            }
            __syncthreads();
        }

        const bool isK = (wc == 0);
        const int colg = (isK ? 0 : C_EMB) + h * 64;
        float bb[4];
        #pragma unroll
        for (int jt = 0; jt < 4; ++jt) bb[jt] = bias[colg + jt * 16 + lrow];
        #pragma unroll
        for (int it = 0; it < 4; ++it)
            #pragma unroll
            for (int jt = 0; jt < 4; ++jt)
                #pragma unroll
                for (int r = 0; r < 4; ++r) {
                    float v = acc[it][jt][r] + bb[jt];
                    acc[it][jt][r] = isK ? elu1(v) : v;
                }

        if (isK) {
            #pragma unroll
            for (int jt = 0; jt < 4; ++jt) {
                float p = 0.0f;
                #pragma unroll
                for (int it = 0; it < 4; ++it)
                    #pragma unroll
                    for (int r = 0; r < 4; ++r) p += acc[it][jt][r];
                p += __shfl_xor(p, 16);
                p += __shfl_xor(p, 32);
                if (quad == 0)
                    atomicAdd(&Ksum[b * C_EMB + h * 64 + jt * 16 + lrow], p);
            }
            #pragma unroll
            for (int it = 0; it < 4; ++it)
                #pragma unroll
                for (int r = 0; r < 4; ++r) {
                    int s = tbase + it * 16 + quad * 4 + r;
                    float2 c0 = tab[s * 32 + lrow];
                    float2 c1 = tab[s * 32 + 16 + lrow];
                    float a0 = acc[it][0][r], a1 = acc[it][1][r];
                    float a2 = acc[it][2][r], a3 = acc[it][3][r];
                    acc[it][0][r] = a0 * c0.x - a2 * c0.y;
                    acc[it][2][r] = a2 * c0.x + a0 * c0.y;
                    acc[it][1][r] = a1 * c1.x - a3 * c1.y;
                    acc[it][3][r] = a3 * c1.x + a1 * c1.y;
                }
        }

        // transposed LDS: K_hi[64][136] @0, K_lo @8704, V_hi @17408, V_lo @26112
        unsigned short* Hd = smem + (isK ? 0 : 17408);
        unsigned short* Ld = Hd + 8704;
        #pragma unroll
        for (int jt = 0; jt < 4; ++jt) {
            int d = jt * 16 + lrow;
            #pragma unroll
            for (int it = 0; it < 4; ++it) {
                int t0loc = wr * 64 + it * 16 + quad * 4;
                ushort4 h4, l4;
                float v0 = acc[it][jt][0], v1 = acc[it][jt][1];
                float v2 = acc[it][jt][2], v3 = acc[it][jt][3];
                h4.x = bf16_rne(v0); l4.x = bf16_rne(v0 - bf16_to_f(h4.x));
                h4.y = bf16_rne(v1); l4.y = bf16_rne(v1 - bf16_to_f(h4.y));
                h4.z = bf16_rne(v2); l4.z = bf16_rne(v2 - bf16_to_f(h4.z));
                h4.w = bf16_rne(v3); l4.w = bf16_rne(v3 - bf16_to_f(h4.w));
                *(ushort4*)&Hd[d * 136 + t0loc] = h4;
                *(ushort4*)&Ld[d * 136 + t0loc] = l4;
            }
        }
    }
    __syncthreads();

    {
        const unsigned short* KH = smem;
        const unsigned short* KL = smem + 8704;
        const unsigned short* VH = smem + 17408;
        const unsigned short* VL = smem + 26112;
        const int mrow = w * 16 + lrow;
        f32x4 macc[4] = {};
        #pragma unroll
        for (int ks = 0; ks < 4; ++ks) {
            int kof = ks * 32 + quad * 8;
            bf16x8 vah = *(const bf16x8*)&VH[mrow * 136 + kof];
            bf16x8 val = *(const bf16x8*)&VL[mrow * 136 + kof];
            #pragma unroll
            for (int jt = 0; jt < 4; ++jt) {
                int nrow = jt * 16 + lrow;
                bf16x8 kbh = *(const bf16x8*)&KH[nrow * 136 + kof];
                bf16x8 kbl = *(const bf16x8*)&KL[nrow * 136 + kof];
                macc[jt] = __builtin_amdgcn_mfma_f32_16x16x32_bf16(vah, kbh, macc[jt], 0, 0, 0);
                macc[jt] = __builtin_amdgcn_mfma_f32_16x16x32_bf16(vah, kbl, macc[jt], 0, 0, 0);
                macc[jt] = __builtin_amdgcn_mfma_f32_16x16x32_bf16(val, kbh, macc[jt], 0, 0, 0);
            }
        }
        const int bh = b * NH + h;
        #pragma unroll
        for (int jt = 0; jt < 4; ++jt)
            #pragma unroll
            for (int r = 0; r < 4; ++r)
                atomicAdd(&Mt[((size_t)bh * 64 + w * 16 + quad * 4 + r) * 64 + jt * 16 + lrow],
                          macc[jt][r]);
    }
}

// ---------------------------------------------------------------------------
// Q GEMM (R7 config): 128x64 tile (one head per block), BK=64, 256 threads,
// wave w owns rows w*32..+31. grid (16 heads, 32 mtiles) = 512 blocks.
// Epilogue: bias, elu+1, den in regs, RoPE, per-wave Qrot LDS,
// Y = (Qrot @ Mt^T)/den, bf16 hi/lo stores.
// ---------------------------------------------------------------------------
__global__ __launch_bounds__(256) void gemm_q(
    const unsigned short* __restrict__ Ah, const unsigned short* __restrict__ Al,
    const unsigned short* __restrict__ Bth, const unsigned short* __restrict__ Btl,
    const float* __restrict__ bias, const float2* __restrict__ tab,
    const float* __restrict__ Ksum, const float* __restrict__ Mt,
    unsigned short* __restrict__ Yh, unsigned short* __restrict__ Yl)
{
    // main loop uses [0,24576); epilogue reuses [0,18432) as per-wave Qrot
    __shared__ unsigned short smem[24576];
    const int h  = blockIdx.x;
    const int m0 = blockIdx.y * 128;
    f32x4 acc[2][4] = {};
    gemm_main_loop_64(Ah, Al, Bth, Btl, smem, m0, h * 64, acc);

    const int tid = threadIdx.x;
    const int w = tid >> 6, lane = tid & 63;
    const int quad = lane >> 4, lrow = lane & 15;
    const int b = m0 >> 11;
    const int tbase = (m0 & 2047) + w * 32;
    const int bh = b * NH + h;

    float bb[4];
    #pragma unroll
    for (int jt = 0; jt < 4; ++jt) bb[jt] = bias[h * 64 + jt * 16 + lrow];
    #pragma unroll
    for (int it = 0; it < 2; ++it)
        #pragma unroll
        for (int jt = 0; jt < 4; ++jt)
            #pragma unroll
            for (int r = 0; r < 4; ++r)
                acc[it][jt][r] = elu1(acc[it][jt][r] + bb[jt]);

    // den (pre-rope), kept in registers
    float ks[4], den_reg[2][4];
    #pragma unroll
    for (int jt = 0; jt < 4; ++jt) ks[jt] = Ksum[b * C_EMB + h * 64 + jt * 16 + lrow];
    #pragma unroll
    for (int it = 0; it < 2; ++it)
        #pragma unroll
        for (int r = 0; r < 4; ++r) {
            float p = acc[it][0][r] * ks[0] + acc[it][1][r] * ks[1]
                    + acc[it][2][r] * ks[2] + acc[it][3][r] * ks[3];
            p += __shfl_xor(p, 1);
            p += __shfl_xor(p, 2);
            p += __shfl_xor(p, 4);
            p += __shfl_xor(p, 8);
            den_reg[it][r] = p;
        }

    // RoPE in registers (pairs jt, jt^2)
    #pragma unroll
    for (int it = 0; it < 2; ++it)
        #pragma unroll
        for (int r = 0; r < 4; ++r) {
            int s = tbase + it * 16 + quad * 4 + r;
            float2 c0 = tab[s * 32 + lrow];
            float2 c1 = tab[s * 32 + 16 + lrow];
            float a0 = acc[it][0][r], a1 = acc[it][1][r];
            float a2 = acc[it][2][r], a3 = acc[it][3][r];
            acc[it][0][r] = a0 * c0.x - a2 * c0.y;
            acc[it][2][r] = a2 * c0.x + a0 * c0.y;
            acc[it][1][r] = a1 * c1.x - a3 * c1.y;
            acc[it][3][r] = a3 * c1.x + a1 * c1.y;
        }

    // Qrot -> per-wave LDS ([32 rows][72], hi then lo). Wave-private region;
    // main loop's final __syncthreads drained cross-wave LDS reads.
    unsigned short* QH = smem + w * 4608;
    unsigned short* QL = QH + 2304;
    #pragma unroll
    for (int it = 0; it < 2; ++it)
        #pragma unroll
        for (int jt = 0; jt < 4; ++jt)
            #pragma unroll
            for (int r = 0; r < 4; ++r) {
                int tloc = it * 16 + quad * 4 + r;
                int d = jt * 16 + lrow;
                float v = acc[it][jt][r];
                unsigned short hh = bf16_rne(v);
                QH[tloc * 72 + d] = hh;
                QL[tloc * 72 + d] = bf16_rne(v - bf16_to_f(hh));
            }

    // Y = (Qrot @ Mt^T) / den
    f32x4 acc2[2][4] = {};
    #pragma unroll
    for (int kc = 0; kc < 2; ++kc) {
        bf16x8 mbh[4], mbl[4];
        #pragma unroll
        for (int jt2 = 0; jt2 < 4; ++jt2) {
            const float* mp = &Mt[((size_t)bh * 64 + jt2 * 16 + lrow) * 64 + kc * 32 + quad * 8];
            #pragma unroll
            for (int e = 0; e < 8; ++e) {
                float x = mp[e];
                unsigned short hh = bf16_rne(x);
                mbh[jt2][e] = (short)hh;
                mbl[jt2][e] = (short)bf16_rne(x - bf16_to_f(hh));
            }
        }
        #pragma unroll
        for (int it2 = 0; it2 < 2; ++it2) {
            int ro = (it2 * 16 + lrow) * 72 + kc * 32 + quad * 8;
            bf16x8 qh = *(const bf16x8*)&QH[ro];
            bf16x8 ql = *(const bf16x8*)&QL[ro];
            #pragma unroll
            for (int jt2 = 0; jt2 < 4; ++jt2) {
                acc2[it2][jt2] = __builtin_amdgcn_mfma_f32_16x16x32_bf16(qh, mbh[jt2], acc2[it2][jt2], 0, 0, 0);
                acc2[it2][jt2] = __builtin_amdgcn_mfma_f32_16x16x32_bf16(qh, mbl[jt2], acc2[it2][jt2], 0, 0, 0);
                acc2[it2][jt2] = __builtin_amdgcn_mfma_f32_16x16x32_bf16(ql, mbh[jt2], acc2[it2][jt2], 0, 0, 0);
            }
        }
    }

    // divide + bf16 hi/lo store
    #pragma unroll
    for (int it2 = 0; it2 < 2; ++it2)
        #pragma unroll
        for (int jt2 = 0; jt2 < 4; ++jt2)
            #pragma unroll
            for (int r = 0; r < 4; ++r) {
                float v = acc2[it2][jt2][r] / den_reg[it2][r];
                size_t o = ((size_t)(m0 + w * 32 + it2 * 16 + quad * 4 + r)) * C_EMB
                         + h * 64 + jt2 * 16 + lrow;
                unsigned short hh = bf16_rne(v);
                Yh[o] = hh;
                Yl[o] = bf16_rne(v - bf16_to_f(hh));
            }
}

// ---------------------------------------------------------------------------
// Output projection GEMM, K-split 2: 128x128 block tile, 4 waves of 64x64
// (kv's ratio), BK=64, grid (8 n, 32 m, 2 k) = 512 blocks = 2048 wave-tiles
// = 8 waves/CU. Partial sums atomicAdd'ed into out (bias pre-written by
// prep). LDS 64 KB -> 2 blocks/CU.
// ---------------------------------------------------------------------------
__global__ __launch_bounds__(256) void gemm_out(
    const unsigned short* __restrict__ Ah, const unsigned short* __restrict__ Al,
    const unsigned short* __restrict__ Bth, const unsigned short* __restrict__ Btl,
    float* __restrict__ out)
{
    __shared__ unsigned short smem[32768];   // 64 KB
    const int tid = threadIdx.x;
    const int w = tid >> 6, lane = tid & 63;
    const int wr = w >> 1, wc = w & 1;
    const int quad = lane >> 4, lrow = lane & 15;
    const int n0 = blockIdx.x * 128;
    const int m0 = blockIdx.y * 128;
    const int kb = blockIdx.z * 512;         // K half

    const unsigned short* src = (w == 0) ? Ah : (w == 1) ? Al : (w == 2) ? Bth : Btl;
    const int srow = lane >> 2, scol = (lane & 3) * 8;
    const size_t rowbase = (w < 2) ? (size_t)(m0 + srow) : (size_t)(n0 + srow);
    const unsigned short* gsrc = src + rowbase * KDIM + scol + kb;
    unsigned short* lbase = &smem[w * 8192];
    const unsigned short* As_h = smem;
    const unsigned short* As_l = smem + 8192;
    const unsigned short* Bs_h = smem + 16384;
    const unsigned short* Bs_l = smem + 24576;

    f32x4 acc[4][4] = {};
    for (int k0 = 0; k0 < 512; k0 += 64) {
        #pragma unroll
        for (int p = 0; p < 2; ++p)
            #pragma unroll
            for (int i = 0; i < 8; ++i)
                __builtin_amdgcn_global_load_lds(
                    (const __attribute__((address_space(1))) unsigned int*)(gsrc + (size_t)i * 16 * KDIM + k0 + p * 32),
                    (__attribute__((address_space(3))) unsigned int*)(lbase + p * 4096 + i * 512),
                    16, 0, 0);
        __syncthreads();
        #pragma unroll
        for (int p = 0; p < 2; ++p) {
            bf16x8 bh[4], bl[4];
            #pragma unroll
            for (int jt = 0; jt < 4; ++jt) {
                int nl = wc * 64 + jt * 16 + lrow;
                bh[jt] = *(const bf16x8*)&Bs_h[p * 4096 + nl * 32 + quad * 8];
                bl[jt] = *(const bf16x8*)&Bs_l[p * 4096 + nl * 32 + quad * 8];
            }
            #pragma unroll
            for (int it = 0; it < 4; ++it) {
                int ml = wr * 64 + it * 16 + lrow;
                bf16x8 ah = *(const bf16x8*)&As_h[p * 4096 + ml * 32 + quad * 8];
                bf16x8 al = *(const bf16x8*)&As_l[p * 4096 + ml * 32 + quad * 8];
                #pragma unroll
                for (int jt = 0; jt < 4; ++jt) {
                    acc[it][jt] = __builtin_amdgcn_mfma_f32_16x16x32_bf16(ah, bh[jt], acc[it][jt], 0, 0, 0);
                    acc[it][jt] = __builtin_amdgcn_mfma_f32_16x16x32_bf16(ah, bl[jt], acc[it][jt], 0, 0, 0);
                    acc[it][jt] = __builtin_amdgcn_mfma_f32_16x16x32_bf16(al, bh[jt], acc[it][jt], 0, 0, 0);
                }
            }
        }
        __syncthreads();
    }

    // atomic accumulate into out (bias already there)
    #pragma unroll
    for (int jt = 0; jt < 4; ++jt) {
        int gc = n0 + wc * 64 + jt * 16 + lrow;
        #pragma unroll
        for (int it = 0; it < 4; ++it) {
            int grb = m0 + wr * 64 + it * 16 + quad * 4;
            #pragma unroll
            for (int r = 0; r < 4; ++r)
                atomicAdd(&out[(size_t)(grb + r) * C_EMB + gc], acc[it][jt][r]);
        }
    }
}

// ---------------------------------------------------------------------------
extern "C" void kernel_launch(void* const* d_in, const int* in_sizes, int n_in,
                              void* d_out, int out_size, void* d_ws, size_t ws_size,
                              hipStream_t stream)
{
    const float* x      = (const float*)d_in[0];
    const float* memory = (const float*)d_in[1];
    const float* q_w    = (const float*)d_in[2];
    const float* q_b    = (const float*)d_in[3];
    const float* kv_w   = (const float*)d_in[4];
    const float* kv_b   = (const float*)d_in[5];
    const float* proj_w = (const float*)d_in[6];
    const float* proj_b = (const float*)d_in[7];

    if (ws_size < WS_FLOATS * sizeof(float)) return;

    float* ws = (float*)d_ws;
    unsigned short* xh   = (unsigned short*)(ws + OFF_XH);
    unsigned short* xl   = (unsigned short*)(ws + OFF_XL);
    unsigned short* mh   = (unsigned short*)(ws + OFF_MEMH);
    unsigned short* ml   = (unsigned short*)(ws + OFF_MEML);
    unsigned short* qwh  = (unsigned short*)(ws + OFF_QWH);
    unsigned short* qwl  = (unsigned short*)(ws + OFF_QWL);
    unsigned short* kvwh = (unsigned short*)(ws + OFF_KVWH);
    unsigned short* kvwl = (unsigned short*)(ws + OFF_KVWL);
    unsigned short* pwh  = (unsigned short*)(ws + OFF_PWH);
    unsigned short* pwl  = (unsigned short*)(ws + OFF_PWL);
    unsigned short* Yh   = (unsigned short*)(ws + OFF_YH);
    unsigned short* Yl   = (unsigned short*)(ws + OFF_YL);
    float*  Ksum = ws + OFF_KSUM;
    float*  Mm   = ws + OFF_MT;
    float2* tab  = (float2*)(ws + OFF_TAB);

    // One prep dispatch: splits + transposes + rope table + zero Ksum/Mt
    // + bias base in d_out (for K-split atomic accumulation)
    prep_kernel<<<PREP_BLOCKS, 256, 0, stream>>>(
        x, memory, q_w, kv_w, proj_w, proj_b,
        xh, xl, mh, ml, qwh, qwl, kvwh, kvwl, pwh, pwl,
        tab, Ksum /* zero_base: Ksum+Mt contiguous */, (float*)d_out);

    // KV GEMM (+elu/Ksum/rope + fused Mt accumulate). No K/V global output.
    gemm_kv<<<dim3(16, 32), 256, 0, stream>>>(mh, ml, kvwh, kvwl, kv_b, tab, Ksum, Mm);
    // Q GEMM (+elu/den/rope + fused Y = Qrot·Mt^T/den) -> Yh/Yl. 512x256.
    gemm_q<<<dim3(16, 32), 256, 0, stream>>>(xh, xl, qwh, qwl, q_b, tab, Ksum, Mm, Yh, Yl);
    // out += Y @ proj_w (K-split 2, atomic; bias pre-written by prep).
    gemm_out<<<dim3(8, 32, 2), 256, 0, stream>>>(Yh, Yl, pwh, pwl, (float*)d_out);
}

// Round 10
// 243.267 us; speedup vs baseline: 1.1153x; 1.0351x over previous
//
#include <hip/hip_runtime.h>
#include <cstddef>
#include <cstdint>

// Problem constants
#define B_SZ  2
#define T_SEQ 2048
#define S_SEQ 2048
#define C_EMB 1024
#define NH    16
#define HD    64
#define KDIM  1024   // inner dim of the three big GEMMs

typedef __attribute__((ext_vector_type(8))) short bf16x8;
typedef __attribute__((ext_vector_type(4))) float f32x4;

// ---------------------------------------------------------------------------
// Workspace layout (float units).
// ---------------------------------------------------------------------------
#define OFF_XH    ((size_t)0)           // [4096,1024] ushort
#define OFF_XL    ((size_t)2097152)
#define OFF_MEMH  ((size_t)4194304)     // [4096,1024] ushort
#define OFF_MEML  ((size_t)6291456)
#define OFF_QWH   ((size_t)8388608)     // [1024,1024] ushort (transposed [N,K])
#define OFF_QWL   ((size_t)8912896)
#define OFF_KVWH  ((size_t)9437184)     // [2048,1024] ushort
#define OFF_KVWL  ((size_t)10485760)
#define OFF_PWH   ((size_t)11534336)    // [1024,1024] ushort
#define OFF_PWL   ((size_t)12058624)
#define OFF_KSUM  ((size_t)12582912)    // [2,1024]      (zeroed by prep)
#define OFF_MT    ((size_t)12584960)    // [32,64,64]    (zeroed by prep)
#define OFF_TAB   ((size_t)12716032)    // [2048,32] float2
#define OFF_YH    ((size_t)12847104)    // [4096,1024] ushort
#define OFF_YL    ((size_t)14944256)
#define WS_FLOATS ((size_t)17041408)    // ~68.2 MB

__device__ __forceinline__ float elu1(float v) {
    return v > 0.0f ? v + 1.0f : __expf(v);
}
__device__ __forceinline__ unsigned short bf16_rne(float x) {
    union { float f; unsigned int u; } v; v.f = x;
    unsigned int u = v.u;
    return (unsigned short)((u + 0x7FFFu + ((u >> 16) & 1u)) >> 16);
}
__device__ __forceinline__ float bf16_to_f(unsigned short h) {
    union { unsigned int u; float f; } v; v.u = ((unsigned int)h) << 16;
    return v.f;
}

// ---------------------------------------------------------------------------
// Unified prep kernel (block-range dispatch).
// ---------------------------------------------------------------------------
#define PREP_BLOCKS 13064

__device__ __forceinline__ void split4_body(
    const float4* __restrict__ in, ushort4* __restrict__ hi,
    ushort4* __restrict__ lo, int i)
{
    float4 v = in[i];
    ushort4 h, l;
    h.x = bf16_rne(v.x); l.x = bf16_rne(v.x - bf16_to_f(h.x));
    h.y = bf16_rne(v.y); l.y = bf16_rne(v.y - bf16_to_f(h.y));
    h.z = bf16_rne(v.z); l.z = bf16_rne(v.z - bf16_to_f(h.z));
    h.w = bf16_rne(v.w); l.w = bf16_rne(v.w - bf16_to_f(h.w));
    hi[i] = h; lo[i] = l;
}

__device__ __forceinline__ void transpose_body(
    const float* __restrict__ W, unsigned short* __restrict__ Wth,
    unsigned short* __restrict__ Wtl, int K, int N, int bx, int by,
    float (*tile)[33])
{
    const int k0 = by * 32, n0 = bx * 32;
    const int tx = threadIdx.x & 31, ty = threadIdx.x >> 5;
    #pragma unroll
    for (int j = 0; j < 4; ++j)
        tile[ty + j * 8][tx] = W[(size_t)(k0 + ty + j * 8) * N + n0 + tx];
    __syncthreads();
    #pragma unroll
    for (int j = 0; j < 4; ++j) {
        float x = tile[tx][ty + j * 8];
        unsigned short h = bf16_rne(x);
        unsigned short l = bf16_rne(x - bf16_to_f(h));
        size_t o = (size_t)(n0 + ty + j * 8) * K + k0 + tx;
        Wth[o] = h; Wtl[o] = l;
    }
}

__global__ __launch_bounds__(256) void prep_kernel(
    const float* __restrict__ x, const float* __restrict__ memory,
    const float* __restrict__ q_w, const float* __restrict__ kv_w,
    const float* __restrict__ proj_w,
    unsigned short* __restrict__ xh, unsigned short* __restrict__ xl,
    unsigned short* __restrict__ mh, unsigned short* __restrict__ ml,
    unsigned short* __restrict__ qwh, unsigned short* __restrict__ qwl,
    unsigned short* __restrict__ kvwh, unsigned short* __restrict__ kvwl,
    unsigned short* __restrict__ pwh, unsigned short* __restrict__ pwl,
    float2* __restrict__ tab, float* __restrict__ zero_base)
{
    __shared__ float tile[32][33];
    const int bid = blockIdx.x;
    const int tid = threadIdx.x;
    if (bid < 4096) {
        split4_body((const float4*)x, (ushort4*)xh, (ushort4*)xl, bid * 256 + tid);
    } else if (bid < 8192) {
        split4_body((const float4*)memory, (ushort4*)mh, (ushort4*)ml, (bid - 4096) * 256 + tid);
    } else if (bid < 9216) {
        int i = bid - 8192;
        transpose_body(q_w, qwh, qwl, 1024, 1024, i & 31, i >> 5, tile);
    } else if (bid < 11264) {
        int i = bid - 9216;
        transpose_body(kv_w, kvwh, kvwl, 1024, 2048, i & 63, i >> 6, tile);
    } else if (bid < 12288) {
        int i = bid - 11264;
        transpose_body(proj_w, pwh, pwl, 1024, 1024, i & 31, i >> 5, tile);
    } else if (bid < 12544) {
        int idx = (bid - 12288) * 256 + tid;    // pos*32 + i
        int pos = idx >> 5, i = idx & 31;
        double invf = exp(-(double)i * (9.210340371976184 / 32.0));  // 10000^(-i/32)
        float arg = (float)((double)pos * invf);
        float sn, cs;
        sincosf(arg, &sn, &cs);
        tab[idx] = make_float2(cs, sn);
    } else {
        int idx = (bid - 12544) * 256 + tid;
        if (idx < 2048 + 131072) zero_base[idx] = 0.0f;   // Ksum + Mt
    }
}

// ---------------------------------------------------------------------------
// 128(M)x64(N) bf16x3 MFMA main loop, BK=64 as two 32-wide K-panels per
// barrier. 4 waves: wave w owns rows w*32..w*32+31, all 64 cols.
// LDS (ushort units): As_h[0,8192) As_l[8192,16384) Bs_h[16384,20480)
// Bs_l[20480,24576) -- 48 KB -> 3 blocks/CU, 12 waves/CU. Fills acc[2][4].
// ---------------------------------------------------------------------------
__device__ __forceinline__ void gemm_main_loop_64(
    const unsigned short* __restrict__ Ah, const unsigned short* __restrict__ Al,
    const unsigned short* __restrict__ Bth, const unsigned short* __restrict__ Btl,
    unsigned short* lds, int m0, int n0, f32x4 acc[2][4])
{
    const int tid = threadIdx.x;
    const int w = tid >> 6, lane = tid & 63;
    const int quad = lane >> 4, lrow = lane & 15;
    const int srow = lane >> 2;
    const int scol = (lane & 3) * 8;

    const unsigned short* src = (w == 0) ? Ah : (w == 1) ? Al : (w == 2) ? Bth : Btl;
    const int rbase = (w < 2) ? m0 : n0;
    const unsigned short* gsrc = src + (size_t)(rbase + srow) * KDIM + scol;
    unsigned short* lbase = (w < 2) ? &lds[w * 8192] : &lds[16384 + (w - 2) * 4096];

    const unsigned short* As_h = lds;
    const unsigned short* As_l = lds + 8192;
    const unsigned short* Bs_h = lds + 16384;
    const unsigned short* Bs_l = lds + 20480;

    for (int k0 = 0; k0 < KDIM; k0 += 64) {
        if (w < 2) {
            #pragma unroll
            for (int p = 0; p < 2; ++p)
                #pragma unroll
                for (int i = 0; i < 8; ++i)
                    __builtin_amdgcn_global_load_lds(
                        (const __attribute__((address_space(1))) unsigned int*)(gsrc + (size_t)i * 16 * KDIM + k0 + p * 32),
                        (__attribute__((address_space(3))) unsigned int*)(lbase + p * 4096 + i * 512),
                        16, 0, 0);
        } else {
            #pragma unroll
            for (int p = 0; p < 2; ++p)
                #pragma unroll
                for (int i = 0; i < 4; ++i)
                    __builtin_amdgcn_global_load_lds(
                        (const __attribute__((address_space(1))) unsigned int*)(gsrc + (size_t)i * 16 * KDIM + k0 + p * 32),
                        (__attribute__((address_space(3))) unsigned int*)(lbase + p * 2048 + i * 512),
                        16, 0, 0);
        }
        __syncthreads();

        #pragma unroll
        for (int p = 0; p < 2; ++p) {
            bf16x8 bh[4], bl[4];
            #pragma unroll
            for (int jt = 0; jt < 4; ++jt) {
                int nl = jt * 16 + lrow;
                bh[jt] = *(const bf16x8*)&Bs_h[p * 2048 + nl * 32 + quad * 8];
                bl[jt] = *(const bf16x8*)&Bs_l[p * 2048 + nl * 32 + quad * 8];
            }
            #pragma unroll
            for (int it = 0; it < 2; ++it) {
                int ml = w * 32 + it * 16 + lrow;
                bf16x8 ah = *(const bf16x8*)&As_h[p * 4096 + ml * 32 + quad * 8];
                bf16x8 al = *(const bf16x8*)&As_l[p * 4096 + ml * 32 + quad * 8];
                #pragma unroll
                for (int jt = 0; jt < 4; ++jt) {
                    acc[it][jt] = __builtin_amdgcn_mfma_f32_16x16x32_bf16(ah, bh[jt], acc[it][jt], 0, 0, 0);
                    acc[it][jt] = __builtin_amdgcn_mfma_f32_16x16x32_bf16(ah, bl[jt], acc[it][jt], 0, 0, 0);
                    acc[it][jt] = __builtin_amdgcn_mfma_f32_16x16x32_bf16(al, bh[jt], acc[it][jt], 0, 0, 0);
                }
            }
        }
        __syncthreads();
    }
}

// ---------------------------------------------------------------------------
// KV GEMM: 128x128 head-paired tile, BK=64 (two 32-panels per barrier),
// fused elu/Ksum/rope + Mt accumulate. grid (16 heads, 32 mtiles).
// ---------------------------------------------------------------------------
__global__ __launch_bounds__(256) void gemm_kv(
    const unsigned short* __restrict__ Ah, const unsigned short* __restrict__ Al,
    const unsigned short* __restrict__ Bth, const unsigned short* __restrict__ Btl,
    const float* __restrict__ bias, const float2* __restrict__ tab,
    float* __restrict__ Ksum, float* __restrict__ Mt)
{
    __shared__ unsigned short smem[34816];
    const int tid = threadIdx.x;
    const int w = tid >> 6, lane = tid & 63;
    const int wr = w >> 1, wc = w & 1;
    const int quad = lane >> 4, lrow = lane & 15;
    const int h  = blockIdx.x;
    const int m0 = blockIdx.y * 128;
    const int b  = m0 >> 11;
    const int tbase = (m0 & 2047) + wr * 64;

    {
        const unsigned short* src = (w == 0) ? Ah : (w == 1) ? Al : (w == 2) ? Bth : Btl;
        const int srow = lane >> 2, scol = (lane & 3) * 8;
        const size_t rowbase = (w < 2) ? (size_t)(m0 + srow) : (size_t)(h * 64 + srow);
        const unsigned short* gsrc = src + rowbase * KDIM + scol;
        const size_t vskip = (w >= 2) ? (size_t)960 * KDIM : 0;
        unsigned short* lbase = &smem[w * 8192];
        const unsigned short* As_h = smem;
        const unsigned short* As_l = smem + 8192;
        const unsigned short* Bs_h = smem + 16384;
        const unsigned short* Bs_l = smem + 24576;

        f32x4 acc[4][4] = {};
        for (int k0 = 0; k0 < KDIM; k0 += 64) {
            #pragma unroll
            for (int p = 0; p < 2; ++p)
                #pragma unroll
                for (int i = 0; i < 8; ++i) {
                    size_t goff = (size_t)i * 16 * KDIM + k0 + p * 32 + ((i >= 4) ? vskip : 0);
                    __builtin_amdgcn_global_load_lds(
                        (const __attribute__((address_space(1))) unsigned int*)(gsrc + goff),
                        (__attribute__((address_space(3))) unsigned int*)(lbase + p * 4096 + i * 512),
                        16, 0, 0);
                }
            __syncthreads();
            #pragma unroll
            for (int p = 0; p < 2; ++p) {
                bf16x8 bh[4], bl[4];
                #pragma unroll
                for (int jt = 0; jt < 4; ++jt) {
                    int nl = wc * 64 + jt * 16 + lrow;
                    bh[jt] = *(const bf16x8*)&Bs_h[p * 4096 + nl * 32 + quad * 8];
                    bl[jt] = *(const bf16x8*)&Bs_l[p * 4096 + nl * 32 + quad * 8];
                }
                #pragma unroll
                for (int it = 0; it < 4; ++it) {
                    int ml = wr * 64 + it * 16 + lrow;
                    bf16x8 ah = *(const bf16x8*)&As_h[p * 4096 + ml * 32 + quad * 8];
                    bf16x8 al = *(const bf16x8*)&As_l[p * 4096 + ml * 32 + quad * 8];
                    #pragma unroll
                    for (int jt = 0; jt < 4; ++jt) {
                        acc[it][jt] = __builtin_amdgcn_mfma_f32_16x16x32_bf16(ah, bh[jt], acc[it][jt], 0, 0, 0);
                        acc[it][jt] = __builtin_amdgcn_mfma_f32_16x16x32_bf16(ah, bl[jt], acc[it][jt], 0, 0, 0);
                        acc[it][jt] = __builtin_amdgcn_mfma_f32_16x16x32_bf16(al, bh[jt], acc[it][jt], 0, 0, 0);
                    }
                }
            }
            __syncthreads();
        }

        const bool isK = (wc == 0);
        const int colg = (isK ? 0 : C_EMB) + h * 64;
        float bb[4];
        #pragma unroll
        for (int jt = 0; jt < 4; ++jt) bb[jt] = bias[colg + jt * 16 + lrow];
        #pragma unroll
        for (int it = 0; it < 4; ++it)
            #pragma unroll
            for (int jt = 0; jt < 4; ++jt)
                #pragma unroll
                for (int r = 0; r < 4; ++r) {
                    float v = acc[it][jt][r] + bb[jt];
                    acc[it][jt][r] = isK ? elu1(v) : v;
                }

        if (isK) {
            #pragma unroll
            for (int jt = 0; jt < 4; ++jt) {
                float p = 0.0f;
                #pragma unroll
                for (int it = 0; it < 4; ++it)
                    #pragma unroll
                    for (int r = 0; r < 4; ++r) p += acc[it][jt][r];
                p += __shfl_xor(p, 16);
                p += __shfl_xor(p, 32);
                if (quad == 0)
                    atomicAdd(&Ksum[b * C_EMB + h * 64 + jt * 16 + lrow], p);
            }
            #pragma unroll
            for (int it = 0; it < 4; ++it)
                #pragma unroll
                for (int r = 0; r < 4; ++r) {
                    int s = tbase + it * 16 + quad * 4 + r;
                    float2 c0 = tab[s * 32 + lrow];
                    float2 c1 = tab[s * 32 + 16 + lrow];
                    float a0 = acc[it][0][r], a1 = acc[it][1][r];
                    float a2 = acc[it][2][r], a3 = acc[it][3][r];
                    acc[it][0][r] = a0 * c0.x - a2 * c0.y;
                    acc[it][2][r] = a2 * c0.x + a0 * c0.y;
                    acc[it][1][r] = a1 * c1.x - a3 * c1.y;
                    acc[it][3][r] = a3 * c1.x + a1 * c1.y;
                }
        }

        // transposed LDS: K_hi[64][136] @0, K_lo @8704, V_hi @17408, V_lo @26112
        unsigned short* Hd = smem + (isK ? 0 : 17408);
        unsigned short* Ld = Hd + 8704;
        #pragma unroll
        for (int jt = 0; jt < 4; ++jt) {
            int d = jt * 16 + lrow;
            #pragma unroll
            for (int it = 0; it < 4; ++it) {
                int t0loc = wr * 64 + it * 16 + quad * 4;
                ushort4 h4, l4;
                float v0 = acc[it][jt][0], v1 = acc[it][jt][1];
                float v2 = acc[it][jt][2], v3 = acc[it][jt][3];
                h4.x = bf16_rne(v0); l4.x = bf16_rne(v0 - bf16_to_f(h4.x));
                h4.y = bf16_rne(v1); l4.y = bf16_rne(v1 - bf16_to_f(h4.y));
                h4.z = bf16_rne(v2); l4.z = bf16_rne(v2 - bf16_to_f(h4.z));
                h4.w = bf16_rne(v3); l4.w = bf16_rne(v3 - bf16_to_f(h4.w));
                *(ushort4*)&Hd[d * 136 + t0loc] = h4;
                *(ushort4*)&Ld[d * 136 + t0loc] = l4;
            }
        }
    }
    __syncthreads();

    {
        const unsigned short* KH = smem;
        const unsigned short* KL = smem + 8704;
        const unsigned short* VH = smem + 17408;
        const unsigned short* VL = smem + 26112;
        const int mrow = w * 16 + lrow;
        f32x4 macc[4] = {};
        #pragma unroll
        for (int ks = 0; ks < 4; ++ks) {
            int kof = ks * 32 + quad * 8;
            bf16x8 vah = *(const bf16x8*)&VH[mrow * 136 + kof];
            bf16x8 val = *(const bf16x8*)&VL[mrow * 136 + kof];
            #pragma unroll
            for (int jt = 0; jt < 4; ++jt) {
                int nrow = jt * 16 + lrow;
                bf16x8 kbh = *(const bf16x8*)&KH[nrow * 136 + kof];
                bf16x8 kbl = *(const bf16x8*)&KL[nrow * 136 + kof];
                macc[jt] = __builtin_amdgcn_mfma_f32_16x16x32_bf16(vah, kbh, macc[jt], 0, 0, 0);
                macc[jt] = __builtin_amdgcn_mfma_f32_16x16x32_bf16(vah, kbl, macc[jt], 0, 0, 0);
                macc[jt] = __builtin_amdgcn_mfma_f32_16x16x32_bf16(val, kbh, macc[jt], 0, 0, 0);
            }
        }
        const int bh = b * NH + h;
        #pragma unroll
        for (int jt = 0; jt < 4; ++jt)
            #pragma unroll
            for (int r = 0; r < 4; ++r)
                atomicAdd(&Mt[((size_t)bh * 64 + w * 16 + quad * 4 + r) * 64 + jt * 16 + lrow],
                          macc[jt][r]);
    }
}

// ---------------------------------------------------------------------------
// Q GEMM, 128x64 tile (one head per block), BK=64 loop. grid (16, 32) = 512
// blocks. Epilogue: bias, elu+1, den in regs, RoPE, per-wave Qrot LDS,
// Y = (Qrot @ Mt^T)/den, bf16 hi/lo stores.
// ---------------------------------------------------------------------------
__global__ __launch_bounds__(256) void gemm_q(
    const unsigned short* __restrict__ Ah, const unsigned short* __restrict__ Al,
    const unsigned short* __restrict__ Bth, const unsigned short* __restrict__ Btl,
    const float* __restrict__ bias, const float2* __restrict__ tab,
    const float* __restrict__ Ksum, const float* __restrict__ Mt,
    unsigned short* __restrict__ Yh, unsigned short* __restrict__ Yl)
{
    // main loop uses [0,24576); epilogue reuses [0,18432) as per-wave Qrot
    __shared__ unsigned short smem[24576];
    const int h  = blockIdx.x;
    const int m0 = blockIdx.y * 128;
    f32x4 acc[2][4] = {};
    gemm_main_loop_64(Ah, Al, Bth, Btl, smem, m0, h * 64, acc);

    const int tid = threadIdx.x;
    const int w = tid >> 6, lane = tid & 63;
    const int quad = lane >> 4, lrow = lane & 15;
    const int b = m0 >> 11;
    const int tbase = (m0 & 2047) + w * 32;
    const int bh = b * NH + h;

    float bb[4];
    #pragma unroll
    for (int jt = 0; jt < 4; ++jt) bb[jt] = bias[h * 64 + jt * 16 + lrow];
    #pragma unroll
    for (int it = 0; it < 2; ++it)
        #pragma unroll
        for (int jt = 0; jt < 4; ++jt)
            #pragma unroll
            for (int r = 0; r < 4; ++r)
                acc[it][jt][r] = elu1(acc[it][jt][r] + bb[jt]);

    // den (pre-rope), kept in registers
    float ks[4], den_reg[2][4];
    #pragma unroll
    for (int jt = 0; jt < 4; ++jt) ks[jt] = Ksum[b * C_EMB + h * 64 + jt * 16 + lrow];
    #pragma unroll
    for (int it = 0; it < 2; ++it)
        #pragma unroll
        for (int r = 0; r < 4; ++r) {
            float p = acc[it][0][r] * ks[0] + acc[it][1][r] * ks[1]
                    + acc[it][2][r] * ks[2] + acc[it][3][r] * ks[3];
            p += __shfl_xor(p, 1);
            p += __shfl_xor(p, 2);
            p += __shfl_xor(p, 4);
            p += __shfl_xor(p, 8);
            den_reg[it][r] = p;
        }

    // RoPE in registers (pairs jt, jt^2)
    #pragma unroll
    for (int it = 0; it < 2; ++it)
        #pragma unroll
        for (int r = 0; r < 4; ++r) {
            int s = tbase + it * 16 + quad * 4 + r;
            float2 c0 = tab[s * 32 + lrow];
            float2 c1 = tab[s * 32 + 16 + lrow];
            float a0 = acc[it][0][r], a1 = acc[it][1][r];
            float a2 = acc[it][2][r], a3 = acc[it][3][r];
            acc[it][0][r] = a0 * c0.x - a2 * c0.y;
            acc[it][2][r] = a2 * c0.x + a0 * c0.y;
            acc[it][1][r] = a1 * c1.x - a3 * c1.y;
            acc[it][3][r] = a3 * c1.x + a1 * c1.y;
        }

    // Qrot -> per-wave LDS ([32 rows][72], hi then lo). Wave-private region;
    // main loop's final __syncthreads drained cross-wave LDS reads.
    unsigned short* QH = smem + w * 4608;
    unsigned short* QL = QH + 2304;
    #pragma unroll
    for (int it = 0; it < 2; ++it)
        #pragma unroll
        for (int jt = 0; jt < 4; ++jt)
            #pragma unroll
            for (int r = 0; r < 4; ++r) {
                int tloc = it * 16 + quad * 4 + r;
                int d = jt * 16 + lrow;
                float v = acc[it][jt][r];
                unsigned short hh = bf16_rne(v);
                QH[tloc * 72 + d] = hh;
                QL[tloc * 72 + d] = bf16_rne(v - bf16_to_f(hh));
            }

    // Y = (Qrot @ Mt^T) / den
    f32x4 acc2[2][4] = {};
    #pragma unroll
    for (int kc = 0; kc < 2; ++kc) {
        bf16x8 mbh[4], mbl[4];
        #pragma unroll
        for (int jt2 = 0; jt2 < 4; ++jt2) {
            const float* mp = &Mt[((size_t)bh * 64 + jt2 * 16 + lrow) * 64 + kc * 32 + quad * 8];
            #pragma unroll
            for (int e = 0; e < 8; ++e) {
                float x = mp[e];
                unsigned short hh = bf16_rne(x);
                mbh[jt2][e] = (short)hh;
                mbl[jt2][e] = (short)bf16_rne(x - bf16_to_f(hh));
            }
        }
        #pragma unroll
        for (int it2 = 0; it2 < 2; ++it2) {
            int ro = (it2 * 16 + lrow) * 72 + kc * 32 + quad * 8;
            bf16x8 qh = *(const bf16x8*)&QH[ro];
            bf16x8 ql = *(const bf16x8*)&QL[ro];
            #pragma unroll
            for (int jt2 = 0; jt2 < 4; ++jt2) {
                acc2[it2][jt2] = __builtin_amdgcn_mfma_f32_16x16x32_bf16(qh, mbh[jt2], acc2[it2][jt2], 0, 0, 0);
                acc2[it2][jt2] = __builtin_amdgcn_mfma_f32_16x16x32_bf16(qh, mbl[jt2], acc2[it2][jt2], 0, 0, 0);
                acc2[it2][jt2] = __builtin_amdgcn_mfma_f32_16x16x32_bf16(ql, mbh[jt2], acc2[it2][jt2], 0, 0, 0);
            }
        }
    }

    // divide + bf16 hi/lo store
    #pragma unroll
    for (int it2 = 0; it2 < 2; ++it2)
        #pragma unroll
        for (int jt2 = 0; jt2 < 4; ++jt2)
            #pragma unroll
            for (int r = 0; r < 4; ++r) {
                float v = acc2[it2][jt2][r] / den_reg[it2][r];
                size_t o = ((size_t)(m0 + w * 32 + it2 * 16 + quad * 4 + r)) * C_EMB
                         + h * 64 + jt2 * 16 + lrow;
                unsigned short hh = bf16_rne(v);
                Yh[o] = hh;
                Yl[o] = bf16_rne(v - bf16_to_f(hh));
            }
}

// ---------------------------------------------------------------------------
// Output projection GEMM, 128x64 tile, BK=64: out = Y @ proj_w + proj_b.
// grid (16 n-tiles, 32 m-tiles) = 512 blocks. LDS 48 KB.
// ---------------------------------------------------------------------------
__global__ __launch_bounds__(256) void gemm_out(
    const unsigned short* __restrict__ Ah, const unsigned short* __restrict__ Al,
    const unsigned short* __restrict__ Bth, const unsigned short* __restrict__ Btl,
    const float* __restrict__ bias, float* __restrict__ out)
{
    __shared__ unsigned short lds[24576];
    const int m0 = blockIdx.y * 128, n0 = blockIdx.x * 64;
    f32x4 acc[2][4] = {};
    gemm_main_loop_64(Ah, Al, Bth, Btl, lds, m0, n0, acc);

    const int tid = threadIdx.x;
    const int w = tid >> 6, lane = tid & 63;
    const int quad = lane >> 4, lrow = lane & 15;

    #pragma unroll
    for (int jt = 0; jt < 4; ++jt) {
        int gc = n0 + jt * 16 + lrow;
        float bb = bias[gc];
        #pragma unroll
        for (int it = 0; it < 2; ++it) {
            int grb = m0 + w * 32 + it * 16 + quad * 4;
            #pragma unroll
            for (int r = 0; r < 4; ++r)
                out[(size_t)(grb + r) * C_EMB + gc] = acc[it][jt][r] + bb;
        }
    }
}

// ---------------------------------------------------------------------------
extern "C" void kernel_launch(void* const* d_in, const int* in_sizes, int n_in,
                              void* d_out, int out_size, void* d_ws, size_t ws_size,
                              hipStream_t stream)
{
    const float* x      = (const float*)d_in[0];
    const float* memory = (const float*)d_in[1];
    const float* q_w    = (const float*)d_in[2];
    const float* q_b    = (const float*)d_in[3];
    const float* kv_w   = (const float*)d_in[4];
    const float* kv_b   = (const float*)d_in[5];
    const float* proj_w = (const float*)d_in[6];
    const float* proj_b = (const float*)d_in[7];

    if (ws_size < WS_FLOATS * sizeof(float)) return;

    float* ws = (float*)d_ws;
    unsigned short* xh   = (unsigned short*)(ws + OFF_XH);
    unsigned short* xl   = (unsigned short*)(ws + OFF_XL);
    unsigned short* mh   = (unsigned short*)(ws + OFF_MEMH);
    unsigned short* ml   = (unsigned short*)(ws + OFF_MEML);
    unsigned short* qwh  = (unsigned short*)(ws + OFF_QWH);
    unsigned short* qwl  = (unsigned short*)(ws + OFF_QWL);
    unsigned short* kvwh = (unsigned short*)(ws + OFF_KVWH);
    unsigned short* kvwl = (unsigned short*)(ws + OFF_KVWL);
    unsigned short* pwh  = (unsigned short*)(ws + OFF_PWH);
    unsigned short* pwl  = (unsigned short*)(ws + OFF_PWL);
    unsigned short* Yh   = (unsigned short*)(ws + OFF_YH);
    unsigned short* Yl   = (unsigned short*)(ws + OFF_YL);
    float*  Ksum = ws + OFF_KSUM;
    float*  Mm   = ws + OFF_MT;
    float2* tab  = (float2*)(ws + OFF_TAB);

    // One prep dispatch: splits + weight transposes + rope table + zero Ksum/Mt
    prep_kernel<<<PREP_BLOCKS, 256, 0, stream>>>(
        x, memory, q_w, kv_w, proj_w,
        xh, xl, mh, ml, qwh, qwl, kvwh, kvwl, pwh, pwl,
        tab, Ksum /* zero_base: Ksum+Mt contiguous */);

    // KV GEMM (+elu/Ksum/rope + fused Mt accumulate). No K/V global output.
    gemm_kv<<<dim3(16, 32), 256, 0, stream>>>(mh, ml, kvwh, kvwl, kv_b, tab, Ksum, Mm);
    // Q GEMM (+elu/den/rope + fused Y = Qrot·Mt^T/den) -> Yh/Yl. 512 blocks.
    gemm_q<<<dim3(16, 32), 256, 0, stream>>>(xh, xl, qwh, qwl, q_b, tab, Ksum, Mm, Yh, Yl);
    // out = Y @ proj_w + proj_b. 512 blocks.
    gemm_out<<<dim3(16, 32), 256, 0, stream>>>(Yh, Yl, pwh, pwl, proj_b, (float*)d_out);
}